// Round 13
// baseline (383.309 us; speedup 1.0000x reference)
//
#include <hip/hip_runtime.h>

// GRU, fp16 MFMA + fp32 accum, T=512 B=1024 I=H=64.
// Round 13 = R11 (311us best) with MFMA operands SWAPPED: W as A-operand
// (rows=units), x/h as B-operand (cols=batch). C-layout: row=unit,
// col=batch -> each lane holds 4 CONSECUTIVE UNITS of one batch row:
//  - exchange write: 4 scattered ds_write_b16 -> ONE ds_write_b64
//  - output store:   4 scattered dwords       -> ONE global_store_dwordx4
//  - h/x B-frag reads: unchanged (2x ds_read_b128 / same xlane loads)
// DS ops/step/lane 6->3, store issues 4->1, shorter pre-barrier drain.
// A-side W layout verified by R10's gx kernel (W-as-A, arow=base+c,
// k=8*g4+e); B-side verified R3..R12. Combine/folds/prefetch/barrier =
// R11 verbatim (R12's acc-split reverted: chaining is pipelined).
// exp2 via __builtin_amdgcn_exp2f (raw v_exp_f32).

typedef _Float16 half8  __attribute__((ext_vector_type(8)));
typedef __fp16   fp16x2 __attribute__((ext_vector_type(2)));
typedef float    f32x4  __attribute__((ext_vector_type(4)));
typedef int      i32x4  __attribute__((ext_vector_type(4)));

#define T_STEPS 512
#define BATCH   1024
#define LOG2E   1.4426950408889634f

struct XBuf { float4 a0, a1, b0, b1; };

__device__ __forceinline__ int pk2(float x, float y) {
    fp16x2 p = __builtin_amdgcn_cvt_pkrtz(x, y);
    return __builtin_bit_cast(int, p);
}

__device__ __forceinline__ half8 cvt8p(const float4& a, const float4& b) {
    i32x4 v;
    v[0] = pk2(a.x, a.y); v[1] = pk2(a.z, a.w);
    v[2] = pk2(b.x, b.y); v[3] = pk2(b.z, b.w);
    return __builtin_bit_cast(half8, v);
}

__device__ __forceinline__ half8 loadw8s(const float* p, float s) {
    const float4* q = (const float4*)p;
    float4 a = q[0], b = q[1];
    half8 h;
    h[0] = (_Float16)(a.x * s); h[1] = (_Float16)(a.y * s);
    h[2] = (_Float16)(a.z * s); h[3] = (_Float16)(a.w * s);
    h[4] = (_Float16)(b.x * s); h[5] = (_Float16)(b.y * s);
    h[6] = (_Float16)(b.z * s); h[7] = (_Float16)(b.w * s);
    return h;
}

__device__ __forceinline__ void block_sync() {
    asm volatile("s_waitcnt lgkmcnt(0)" ::: "memory");
    __builtin_amdgcn_s_barrier();
    asm volatile("" ::: "memory");
}

#define MFMA16(A, B, C) __builtin_amdgcn_mfma_f32_16x16x32_f16((A), (B), (C), 0, 0, 0)

__global__ __launch_bounds__(256, 1)
void gru_fused_kernel(const float* __restrict__ X,     // [T,B,64]
                      const float* __restrict__ W_ih,  // [192,64]
                      const float* __restrict__ W_hh,  // [192,64]
                      const float* __restrict__ b_ih,  // [192]
                      const float* __restrict__ b_hh,  // [192]
                      float* __restrict__ out)         // [T*B*64] ++ [B*64]
{
    const int tid   = threadIdx.x;
    const int wq    = tid >> 6;        // wave: units [16wq,16wq+16)
    const int l     = tid & 63;
    const int c     = l & 15;          // batch row (B-col / C-col)
    const int g4    = l >> 4;          // lane group (k-slot / C-row group)
    const int ar    = 16 * wq + c;     // A row (unit) for W fragments
    const int ub    = 16 * wq + 4 * g4;// unit base of this lane's 4 C rows
    const int brow0 = blockIdx.x * 16;

    __shared__ __align__(16) _Float16 hbuf[2][16][72];  // [batch][unit], pad 72

    const float sRZ = -LOG2E;
    const float sN  = 2.0f * LOG2E;

    // ---- 12 W A-fragments (rows = units), fp16, pre-scaled, loaded once ----
    const half8 Arx0 = loadw8s(W_ih + (ar)       * 64 +      8 * g4, sRZ);
    const half8 Arx1 = loadw8s(W_ih + (ar)       * 64 + 32 + 8 * g4, sRZ);
    const half8 Azx0 = loadw8s(W_ih + (64 + ar)  * 64 +      8 * g4, sRZ);
    const half8 Azx1 = loadw8s(W_ih + (64 + ar)  * 64 + 32 + 8 * g4, sRZ);
    const half8 Anx0 = loadw8s(W_ih + (128 + ar) * 64 +      8 * g4, sN);
    const half8 Anx1 = loadw8s(W_ih + (128 + ar) * 64 + 32 + 8 * g4, sN);
    const half8 Arh0 = loadw8s(W_hh + (ar)       * 64 +      8 * g4, sRZ);
    const half8 Arh1 = loadw8s(W_hh + (ar)       * 64 + 32 + 8 * g4, sRZ);
    const half8 Azh0 = loadw8s(W_hh + (64 + ar)  * 64 +      8 * g4, sRZ);
    const half8 Azh1 = loadw8s(W_hh + (64 + ar)  * 64 + 32 + 8 * g4, sRZ);
    const half8 Anh0 = loadw8s(W_hh + (128 + ar) * 64 +      8 * g4, sN);
    const half8 Anh1 = loadw8s(W_hh + (128 + ar) * 64 + 32 + 8 * g4, sN);

    // ---- biases, per-lane vectors over the 4 units [ub, ub+4) ----
    const float4 bir = *(const float4*)(b_ih + ub);
    const float4 bhr = *(const float4*)(b_hh + ub);
    const float4 biz = *(const float4*)(b_ih + 64 + ub);
    const float4 bhz = *(const float4*)(b_hh + 64 + ub);
    const float4 bin = *(const float4*)(b_ih + 128 + ub);
    const float4 bhn = *(const float4*)(b_hh + 128 + ub);
    f32x4 rb4, zb4, nxb4, nhb4;
    rb4[0] = sRZ * (bir.x + bhr.x); rb4[1] = sRZ * (bir.y + bhr.y);
    rb4[2] = sRZ * (bir.z + bhr.z); rb4[3] = sRZ * (bir.w + bhr.w);
    zb4[0] = sRZ * (biz.x + bhz.x); zb4[1] = sRZ * (biz.y + bhz.y);
    zb4[2] = sRZ * (biz.z + bhz.z); zb4[3] = sRZ * (biz.w + bhz.w);
    nxb4[0] = sN * bin.x; nxb4[1] = sN * bin.y;
    nxb4[2] = sN * bin.z; nxb4[3] = sN * bin.w;
    nhb4[0] = sN * bhn.x; nhb4[1] = sN * bhn.y;
    nhb4[2] = sN * bhn.z; nhb4[3] = sN * bhn.w;

    // ---- addressing: lane part for X; running output pointer ----
    const int xlane = (brow0 + c) * 64 + 8 * g4;
    float* outp = out + (size_t)((brow0 + c) * 64 + ub);

#define ISSUE_X(XB, TN) do {                                                  \
        const float* px_ = X + (size_t)(TN) * (BATCH * 64) + xlane;           \
        const float4* q_ = (const float4*)px_;                                \
        (XB).a0 = q_[0]; (XB).a1 = q_[1];                                     \
        (XB).b0 = q_[8]; (XB).b1 = q_[9];                                     \
    } while (0)

    XBuf xb0, xb1;
    ISSUE_X(xb0, 0);
    ISSUE_X(xb1, 1);

    // zero h(0) buffers (both phases)
    for (int k = tid; k < 2 * 16 * 72; k += 256)
        ((_Float16*)hbuf)[k] = (_Float16)0.f;
    __syncthreads();

    f32x4 hp = {0.f, 0.f, 0.f, 0.f};   // h for (units ub..ub+3, batch c)

    // STEP: P is a LITERAL parity.
#define STEP(T, P, XA) do {                                                   \
        /* h B-frag reads first; latency covered by x-work below */           \
        const half8 hf0 = *(const half8*)&hbuf[P][c][8 * g4];                 \
        const half8 hf1 = *(const half8*)&hbuf[P][c][32 + 8 * g4];            \
        const half8 xf0 = cvt8p((XA).a0, (XA).a1);                            \
        const half8 xf1 = cvt8p((XA).b0, (XA).b1);                            \
        { int tn_ = (T) + 2; if (tn_ > T_STEPS - 1) tn_ = T_STEPS - 1;        \
          ISSUE_X(XA, tn_); }                                                 \
        /* chained accumulators (R11 structure): x-side then h-side */        \
        f32x4 cr  = MFMA16(Arx0, xf0, rb4);                                   \
        cr        = MFMA16(Arx1, xf1, cr);                                    \
        f32x4 cz  = MFMA16(Azx0, xf0, zb4);                                   \
        cz        = MFMA16(Azx1, xf1, cz);                                    \
        f32x4 cnx = MFMA16(Anx0, xf0, nxb4);                                  \
        cnx       = MFMA16(Anx1, xf1, cnx);                                   \
        cr        = MFMA16(Arh0, hf0, cr);                                    \
        cr        = MFMA16(Arh1, hf1, cr);                                    \
        cz        = MFMA16(Azh0, hf0, cz);                                    \
        cz        = MFMA16(Azh1, hf1, cz);                                    \
        f32x4 cnh = MFMA16(Anh0, hf0, nhb4);                                  \
        cnh       = MFMA16(Anh1, hf1, cnh);                                   \
        f32x4 hn4;                                                            \
        _Pragma("unroll")                                                     \
        for (int i = 0; i < 4; ++i) {                                         \
            const float rv = __builtin_amdgcn_rcpf(                           \
                                 1.f + __builtin_amdgcn_exp2f(cr[i]));        \
            const float zv = __builtin_amdgcn_rcpf(                           \
                                 1.f + __builtin_amdgcn_exp2f(cz[i]));        \
            const float npre = fmaf(rv, cnh[i], cnx[i]);                      \
            const float e  = __builtin_amdgcn_exp2f(npre);                    \
            const float nv = 1.f - 2.f * __builtin_amdgcn_rcpf(e + 1.f);      \
            const float hn = fmaf(zv, hp[i] - nv, nv);                        \
            hp[i] = hn;                                                       \
            hn4[i] = hn;                                                      \
        }                                                                     \
        /* ONE ds_write_b64: 4 contiguous units at row c */                   \
        { uint2 hw;                                                           \
          hw.x = (unsigned)pk2(hn4[0], hn4[1]);                               \
          hw.y = (unsigned)pk2(hn4[2], hn4[3]);                               \
          *(uint2*)&hbuf[(P) ^ 1][c][ub] = hw; }                              \
        /* ONE global_store_dwordx4 */                                        \
        *(f32x4*)outp = hn4;                                                  \
        outp += BATCH * 64;                                                   \
        block_sync();                                                         \
    } while (0)

    #pragma unroll 1
    for (int t = 0; t < T_STEPS; t += 2) {
        STEP(t,     0, xb0);
        STEP(t + 1, 1, xb1);
    }

    // h_last: outp now points at the [1,B,H] tail + lane offset
    *(f32x4*)outp = hp;

#undef STEP
#undef ISSUE_X
}

extern "C" void kernel_launch(void* const* d_in, const int* in_sizes, int n_in,
                              void* d_out, int out_size, void* d_ws, size_t ws_size,
                              hipStream_t stream) {
    const float* X    = (const float*)d_in[0];
    const float* W_ih = (const float*)d_in[1];
    const float* W_hh = (const float*)d_in[2];
    const float* b_ih = (const float*)d_in[3];
    const float* b_hh = (const float*)d_in[4];
    float* out = (float*)d_out;

    gru_fused_kernel<<<dim3(BATCH / 16), dim3(256), 0, stream>>>(
        X, W_ih, W_hh, b_ih, b_hh, out);
}

// Round 14
// 312.419 us; speedup vs baseline: 1.2269x; 1.2269x over previous
//
#include <hip/hip_runtime.h>

// GRU, fp16 MFMA + fp32 accum, T=512 B=1024 I=H=64.
// Round 14 = EXACT REVERT to Round 11 (session best: 311us bench / 386us
// rocprof, absmax 0.0039). R12 (acc split, +3.5%) and R13 (operand swap,
// +16%) both regressed; all structural alternatives measured worse
// (R4 +27%, R6 +118%, R7 +85%, R8/R10 split +13% total).
// Structure: 64 blocks x 4 waves; block owns 16 batch rows; wave owns 16
// units. Per step: 2x ds_read_b128 (h, all 64 units), 4x v_cvt_pkrtz (x),
// 12 MFMA (x-side chained ahead of h-side, hidden under ds_read latency),
// exp2-folded combine (log2e pre-scaled into W frags + biases),
// 4x ds_write_b16 + 4 stores, one lgkmcnt(0)+s_barrier. 2-deep X prefetch.
// Wall = 512 x steplat; steplat ~1810 cyc = dependency-latency floor of
// the barrier-synced exchange structure (MfmaUtil 2.6%, VALU 9.5%, HBM 2%).
// C-layout (verified R3..R13): col(unit)=lane&15, row(batch)=(lane>>4)*4+reg.

typedef _Float16 half8  __attribute__((ext_vector_type(8)));
typedef __fp16   fp16x2 __attribute__((ext_vector_type(2)));
typedef float    f32x4  __attribute__((ext_vector_type(4)));
typedef int      i32x4  __attribute__((ext_vector_type(4)));

#define T_STEPS 512
#define BATCH   1024
#define LOG2E   1.4426950408889634f

struct XBuf { float4 a0, a1, b0, b1; };

__device__ __forceinline__ int pk2(float x, float y) {
    fp16x2 p = __builtin_amdgcn_cvt_pkrtz(x, y);
    return __builtin_bit_cast(int, p);
}

__device__ __forceinline__ half8 cvt8p(const float4& a, const float4& b) {
    i32x4 v;
    v[0] = pk2(a.x, a.y); v[1] = pk2(a.z, a.w);
    v[2] = pk2(b.x, b.y); v[3] = pk2(b.z, b.w);
    return __builtin_bit_cast(half8, v);
}

__device__ __forceinline__ half8 loadw8s(const float* p, float s) {
    const float4* q = (const float4*)p;
    float4 a = q[0], b = q[1];
    half8 h;
    h[0] = (_Float16)(a.x * s); h[1] = (_Float16)(a.y * s);
    h[2] = (_Float16)(a.z * s); h[3] = (_Float16)(a.w * s);
    h[4] = (_Float16)(b.x * s); h[5] = (_Float16)(b.y * s);
    h[6] = (_Float16)(b.z * s); h[7] = (_Float16)(b.w * s);
    return h;
}

__device__ __forceinline__ void block_sync() {
    asm volatile("s_waitcnt lgkmcnt(0)" ::: "memory");
    __builtin_amdgcn_s_barrier();
    asm volatile("" ::: "memory");
}

#define MFMA16(A, B, C) __builtin_amdgcn_mfma_f32_16x16x32_f16((A), (B), (C), 0, 0, 0)

__global__ __launch_bounds__(256, 1)
void gru_fused_kernel(const float* __restrict__ X,     // [T,B,64]
                      const float* __restrict__ W_ih,  // [192,64]
                      const float* __restrict__ W_hh,  // [192,64]
                      const float* __restrict__ b_ih,  // [192]
                      const float* __restrict__ b_hh,  // [192]
                      float* __restrict__ out)         // [T*B*64] ++ [B*64]
{
    const int tid   = threadIdx.x;
    const int wq    = tid >> 6;       // unit group
    const int l     = tid & 63;
    const int c     = l & 15;         // batch row within tile / B-col
    const int g4    = l >> 4;         // lane group
    const int u     = wq * 16 + c;    // hidden-unit column
    const int brow0 = blockIdx.x * 16;

    __shared__ __align__(16) _Float16 hbuf[2][16][72];

    const float sRZ = -LOG2E;
    const float sN  = 2.0f * LOG2E;

    // ---- 12 W B-fragments, fp16, pre-scaled, loaded once (48 VGPR) ----
    const half8 Brx0 = loadw8s(W_ih + (u)       * 64 +      8 * g4, sRZ);
    const half8 Brx1 = loadw8s(W_ih + (u)       * 64 + 32 + 8 * g4, sRZ);
    const half8 Bzx0 = loadw8s(W_ih + (64 + u)  * 64 +      8 * g4, sRZ);
    const half8 Bzx1 = loadw8s(W_ih + (64 + u)  * 64 + 32 + 8 * g4, sRZ);
    const half8 Bnx0 = loadw8s(W_ih + (128 + u) * 64 +      8 * g4, sN);
    const half8 Bnx1 = loadw8s(W_ih + (128 + u) * 64 + 32 + 8 * g4, sN);
    const half8 Brh0 = loadw8s(W_hh + (u)       * 64 +      8 * g4, sRZ);
    const half8 Brh1 = loadw8s(W_hh + (u)       * 64 + 32 + 8 * g4, sRZ);
    const half8 Bzh0 = loadw8s(W_hh + (64 + u)  * 64 +      8 * g4, sRZ);
    const half8 Bzh1 = loadw8s(W_hh + (64 + u)  * 64 + 32 + 8 * g4, sRZ);
    const half8 Bnh0 = loadw8s(W_hh + (128 + u) * 64 +      8 * g4, sN);
    const half8 Bnh1 = loadw8s(W_hh + (128 + u) * 64 + 32 + 8 * g4, sN);

    const float rb  = sRZ * (b_ih[u]      + b_hh[u]);
    const float zb  = sRZ * (b_ih[64 + u] + b_hh[64 + u]);
    const float nxb = sN * b_ih[128 + u];
    const float nhb = sN * b_hh[128 + u];

#define ISSUE_X(XB, T) do {                                                   \
        const float* px_ = X + ((size_t)(T) * BATCH + brow0 + c) * 64 + 8 * g4; \
        (XB).a0 = ((const float4*)px_)[0];                                    \
        (XB).a1 = ((const float4*)px_)[1];                                    \
        (XB).b0 = ((const float4*)(px_ + 32))[0];                             \
        (XB).b1 = ((const float4*)(px_ + 32))[1];                             \
    } while (0)

    XBuf xb0, xb1;
    ISSUE_X(xb0, 0);
    ISSUE_X(xb1, 1);

    // zero h(0) buffers
    for (int k = tid; k < 2 * 16 * 72; k += 256)
        ((_Float16*)hbuf)[k] = (_Float16)0.f;
    __syncthreads();

    f32x4 hp = {0.f, 0.f, 0.f, 0.f};

#define STEP(T, XA) do {                                                      \
        const int p_ = (T) & 1;                                               \
        /* issue h reads FIRST: latency covered by x-work below */            \
        const half8 hf0 = *(const half8*)&hbuf[p_][c][8 * g4];                \
        const half8 hf1 = *(const half8*)&hbuf[p_][c][32 + 8 * g4];           \
        /* x fragment (loaded 2 steps ago, in regs) + refill prefetch */      \
        const half8 xf0 = cvt8p((XA).a0, (XA).a1);                            \
        const half8 xf1 = cvt8p((XA).b0, (XA).b1);                            \
        { int tn_ = (T) + 2; if (tn_ > T_STEPS - 1) tn_ = T_STEPS - 1;        \
          ISSUE_X(XA, tn_); }                                                 \
        f32x4 cr  = {rb, rb, rb, rb};                                         \
        f32x4 cz  = {zb, zb, zb, zb};                                         \
        f32x4 cnx = {nxb, nxb, nxb, nxb};                                     \
        f32x4 cnh = {nhb, nhb, nhb, nhb};                                     \
        /* x-MFMAs: independent of h, execute inside the ds_read window */    \
        cr  = MFMA16(xf0, Brx0, cr);  cr  = MFMA16(xf1, Brx1, cr);            \
        cz  = MFMA16(xf0, Bzx0, cz);  cz  = MFMA16(xf1, Bzx1, cz);            \
        cnx = MFMA16(xf0, Bnx0, cnx); cnx = MFMA16(xf1, Bnx1, cnx);           \
        /* h-MFMAs (compiler places the lgkmcnt wait right before these) */   \
        cr  = MFMA16(hf0, Brh0, cr);  cr  = MFMA16(hf1, Brh1, cr);            \
        cz  = MFMA16(hf0, Bzh0, cz);  cz  = MFMA16(hf1, Bzh1, cz);            \
        cnh = MFMA16(hf0, Bnh0, cnh); cnh = MFMA16(hf1, Bnh1, cnh);           \
        _Pragma("unroll")                                                     \
        for (int i = 0; i < 4; ++i) {                                         \
            const float rv = __builtin_amdgcn_rcpf(1.f + exp2f(cr[i]));       \
            const float zv = __builtin_amdgcn_rcpf(1.f + exp2f(cz[i]));       \
            const float npre = fmaf(rv, cnh[i], cnx[i]);                      \
            const float e  = exp2f(npre);                                     \
            const float nv = 1.f - 2.f * __builtin_amdgcn_rcpf(e + 1.f);      \
            const float hn = fmaf(zv, hp[i] - nv, nv);                        \
            hp[i] = hn;                                                       \
            hbuf[p_ ^ 1][4 * g4 + i][u] = (_Float16)hn;                       \
            out[((size_t)(T) * BATCH + brow0 + 4 * g4 + i) * 64 + u] = hn;    \
        }                                                                     \
        block_sync();                                                         \
    } while (0)

    #pragma unroll 1
    for (int t = 0; t < T_STEPS; t += 2) {
        STEP(t,     xb0);
        STEP(t + 1, xb1);
    }

    #pragma unroll
    for (int i = 0; i < 4; ++i)
        out[(size_t)T_STEPS * BATCH * 64 + (brow0 + 4 * g4 + i) * 64 + u] = hp[i];

#undef STEP
#undef ISSUE_X
}

extern "C" void kernel_launch(void* const* d_in, const int* in_sizes, int n_in,
                              void* d_out, int out_size, void* d_ws, size_t ws_size,
                              hipStream_t stream) {
    const float* X    = (const float*)d_in[0];
    const float* W_ih = (const float*)d_in[1];
    const float* W_hh = (const float*)d_in[2];
    const float* b_ih = (const float*)d_in[3];
    const float* b_hh = (const float*)d_in[4];
    float* out = (float*)d_out;

    gru_fused_kernel<<<dim3(BATCH / 16), dim3(256), 0, stream>>>(
        X, W_ih, W_hh, b_ih, b_hh, out);
}